// Round 2
// baseline (128.812 us; speedup 1.0000x reference)
//
#include <hip/hip_runtime.h>

#define HH 14
#define WW 14
#define P 196          // HH*WW
#define SENT 196
#define CTOT 2048
#define NCHUNK 16
#define CCHUNK 128     // CTOT/NCHUNK
#define Q4 49          // P/4 float4 per channel row

// d_ws layout: [0,256) per-batch arrival counters (64 ints, zeroed by memset
// each call); [256, 256 + 1024*196*4) partial sums.

__global__ __launch_bounds__(256) void fused_kernel(const float* __restrict__ fms,
                                                    int* __restrict__ counters,
                                                    float* __restrict__ partials,
                                                    int* __restrict__ out) {
    const int blk = blockIdx.x;
    const int b = blk >> 4;       // batch
    const int k = blk & 15;       // channel chunk
    const float4* __restrict__ base =
        (const float4*)(fms + ((size_t)b * CTOT + (size_t)k * CCHUNK) * P);

    __shared__ float lds[5 * P];
    __shared__ int flag;
    const int t = threadIdx.x;

    // ---- phase 1: stream 128 channels, partial-sum per pixel ----
    if (t < 5 * Q4) {             // 245 active lanes
        const int q = t % Q4;     // float4 column within a channel row
        const int r = t / Q4;     // row-group 0..4
        float4 acc = {0.f, 0.f, 0.f, 0.f};
        #pragma unroll 4
        for (int c = r; c < CCHUNK; c += 5) {
            float4 v = base[c * Q4 + q];
            acc.x += v.x; acc.y += v.y; acc.z += v.z; acc.w += v.w;
        }
        const int o = r * P + q * 4;
        lds[o + 0] = acc.x; lds[o + 1] = acc.y;
        lds[o + 2] = acc.z; lds[o + 3] = acc.w;
    }
    __syncthreads();
    if (t < P) {
        float s = lds[t] + lds[P + t] + lds[2 * P + t] + lds[3 * P + t] + lds[4 * P + t];
        partials[(size_t)blk * P + t] = s;
    }
    __threadfence();              // release this block's partials (device scope)
    __syncthreads();              // all waves' stores+fences done
    if (t == 0) flag = atomicAdd(&counters[b], 1);
    __syncthreads();
    if (flag != NCHUNK - 1 || t >= 64) return;   // only wave 0 of last arrival

    // ---- phase 2: single-wave finisher (no block barriers from here) ----
    __threadfence();              // acquire other blocks' partials
    const int l = t;              // lane 0..63; lanes 0..48 own pixels 4l..4l+3

    float4 a4 = {0.f, 0.f, 0.f, 0.f};
    if (l < Q4) {
        const float* pb = partials + (size_t)b * NCHUNK * P + 4 * l;
        #pragma unroll
        for (int kk = 0; kk < NCHUNK; ++kk) {
            float4 v = *(const float4*)(pb + kk * P);
            a4.x += v.x; a4.y += v.y; a4.z += v.z; a4.w += v.w;
        }
    }
    float mx = (l < Q4) ? fmaxf(fmaxf(a4.x, a4.y), fmaxf(a4.z, a4.w)) : -1e30f;
    #pragma unroll
    for (int off = 32; off >= 1; off >>= 1) mx = fmaxf(mx, __shfl_xor(mx, off));
    const float thr = mx * 0.3f;

    int* lab = (int*)lds;         // [196] reuse LDS
    int* cnt = ((int*)lds) + 256; // [196]

    int mymask = 0;
    float av[4] = {a4.x, a4.y, a4.z, a4.w};
    if (l < Q4) {
        #pragma unroll
        for (int j = 0; j < 4; ++j) {
            const int p = 4 * l + j;
            const bool m = av[j] > thr;
            mymask |= (m ? 1 : 0) << j;
            lab[p] = m ? p : SENT;
        }
    }
    asm volatile("s_waitcnt lgkmcnt(0)" ::: "memory");

    // Gauss-Seidel min-label propagation (8-connectivity); order-independent
    // fixed point == reference's Jacobi fixed point.
    for (;;) {
        int changed = 0;
        if (mymask) {
            #pragma unroll
            for (int j = 0; j < 4; ++j) {
                if (mymask & (1 << j)) {
                    const int p = 4 * l + j;
                    const int row = p / WW, col = p % WW;
                    const int cur = lab[p];
                    int m2 = cur;
                    #pragma unroll
                    for (int dr = -1; dr <= 1; ++dr) {
                        const int rr = row + dr;
                        if (rr < 0 || rr >= HH) continue;
                        #pragma unroll
                        for (int dc = -1; dc <= 1; ++dc) {
                            const int cc = col + dc;
                            if (cc < 0 || cc >= WW) continue;
                            m2 = min(m2, lab[rr * WW + cc]);
                        }
                    }
                    if (m2 < cur) { lab[p] = m2; changed = 1; }
                }
            }
        }
        asm volatile("s_waitcnt lgkmcnt(0)" ::: "memory");
        if (!__any(changed)) break;
    }

    // per-label counts
    if (l < Q4) {
        #pragma unroll
        for (int j = 0; j < 4; ++j) cnt[4 * l + j] = 0;
    }
    asm volatile("s_waitcnt lgkmcnt(0)" ::: "memory");
    if (l < Q4) {
        #pragma unroll
        for (int j = 0; j < 4; ++j)
            if (mymask & (1 << j)) atomicAdd(&cnt[lab[4 * l + j]], 1);
    }
    asm volatile("s_waitcnt lgkmcnt(0)" ::: "memory");

    // argmax(count), ties -> smallest label: key = cnt*256 + (255 - label)
    int key = 0;
    if (l < Q4) {
        #pragma unroll
        for (int j = 0; j < 4; ++j) {
            const int p = 4 * l + j;
            key = max(key, cnt[p] * 256 + (255 - p));
        }
    }
    #pragma unroll
    for (int off = 32; off >= 1; off >>= 1) key = max(key, __shfl_xor(key, off));
    const int best = 255 - (key & 255);
    const int bcnt = key >> 8;

    // bbox of selected component (unmasked pixels have lab==SENT != best)
    int mnr = HH, mxr = -1, mnc = WW, mxc = -1;
    if (l < Q4 && bcnt > 0) {
        #pragma unroll
        for (int j = 0; j < 4; ++j) {
            const int p = 4 * l + j;
            if (lab[p] == best) {
                const int row = p / WW, col = p % WW;
                mnr = min(mnr, row); mxr = max(mxr, row);
                mnc = min(mnc, col); mxc = max(mxc, col);
            }
        }
    }
    #pragma unroll
    for (int off = 32; off >= 1; off >>= 1) {
        mnr = min(mnr, __shfl_xor(mnr, off));
        mxr = max(mxr, __shfl_xor(mxr, off));
        mnc = min(mnc, __shfl_xor(mnc, off));
        mxc = max(mxc, __shfl_xor(mxc, off));
    }

    if (l == 0) {
        if (bcnt == 0) { mnr = 0; mxr = HH - 1; mnc = 0; mxc = WW - 1; }
        out[b * 4 + 0] = max(mnr * 32 - 1, 0);
        out[b * 4 + 1] = max(mnc * 32 - 1, 0);
        out[b * 4 + 2] = (mxr + 1) * 32 - 1;
        out[b * 4 + 3] = (mxc + 1) * 32 - 1;
    }
}

extern "C" void kernel_launch(void* const* d_in, const int* in_sizes, int n_in,
                              void* d_out, int out_size, void* d_ws, size_t ws_size,
                              hipStream_t stream) {
    const float* fms = (const float*)d_in[0];
    int* out = (int*)d_out;
    int* counters = (int*)d_ws;                       // 64 ints
    float* partials = (float*)((char*)d_ws + 256);    // 1024*196 floats

    hipMemsetAsync(counters, 0, 256, stream);         // deterministic arrival counts
    fused_kernel<<<dim3(64 * NCHUNK), dim3(256), 0, stream>>>(fms, counters, partials, out);
}

// Round 3
// 38.783 us; speedup vs baseline: 3.3214x; 3.3214x over previous
//
#include <hip/hip_runtime.h>

#define HH 14
#define WW 14
#define P 196          // HH*WW
#define SENT 196
#define CTOT 2048
#define NCHUNK 32
#define CCHUNK 64      // CTOT/NCHUNK
#define Q4 49          // P/4 float4 per channel row

// ---------------- kernel 1: partial channel sums ----------------
// grid = 64*NCHUNK = 2048 blocks (8 blocks/CU -> 100% wave occupancy),
// 256 threads. Block (b,k) sums channels [k*CCHUNK,(k+1)*CCHUNK) into
// partials[b*NCHUNK+k][196]. Each block streams a contiguous 50 KB region.
__global__ __launch_bounds__(256) void chansum_kernel(const float* __restrict__ fms,
                                                      float* __restrict__ partials) {
    const int blk = blockIdx.x;
    const int b = blk >> 5;       // /NCHUNK
    const int k = blk & 31;       // %NCHUNK
    const float4* __restrict__ base =
        (const float4*)(fms + ((size_t)b * CTOT + (size_t)k * CCHUNK) * P);

    __shared__ float lds[5 * P];
    const int t = threadIdx.x;

    if (t < 5 * Q4) {             // 245 active lanes
        const int q = t % Q4;     // float4 column within a channel row
        const int r = t / Q4;     // row-group 0..4
        float4 acc = {0.f, 0.f, 0.f, 0.f};
        #pragma unroll 4
        for (int c = r; c < CCHUNK; c += 5) {
            float4 v = base[c * Q4 + q];
            acc.x += v.x; acc.y += v.y; acc.z += v.z; acc.w += v.w;
        }
        const int o = r * P + q * 4;
        lds[o + 0] = acc.x; lds[o + 1] = acc.y;
        lds[o + 2] = acc.z; lds[o + 3] = acc.w;
    }
    __syncthreads();
    if (t < P) {
        float s = lds[t] + lds[P + t] + lds[2 * P + t] + lds[3 * P + t] + lds[4 * P + t];
        partials[(size_t)blk * P + t] = s;
    }
}

// ---------------- kernel 2: threshold + CC + bbox, single wave ----------------
// grid = 64 blocks x 64 threads. Wave-synchronous: no __syncthreads, LDS
// ordering via s_waitcnt lgkmcnt(0). Logic identical to the (passing)
// round-2 finisher.
__global__ __launch_bounds__(64) void bbox_kernel(const float* __restrict__ partials,
                                                  int* __restrict__ out) {
    const int b = blockIdx.x;
    const int l = threadIdx.x;    // lane 0..63; lanes 0..48 own pixel quads

    __shared__ int lab[P];
    __shared__ int cnt[256];

    // sum partials -> attention quad per lane (sum vs mean: threshold is
    // relative, and the margin is ~54 sigma, so rounding can't flip the mask)
    float4 a4 = {0.f, 0.f, 0.f, 0.f};
    if (l < Q4) {
        const float* pb = partials + (size_t)b * NCHUNK * P + 4 * l;
        #pragma unroll 8
        for (int kk = 0; kk < NCHUNK; ++kk) {
            float4 v = *(const float4*)(pb + kk * P);
            a4.x += v.x; a4.y += v.y; a4.z += v.z; a4.w += v.w;
        }
    }
    float mx = (l < Q4) ? fmaxf(fmaxf(a4.x, a4.y), fmaxf(a4.z, a4.w)) : -1e30f;
    #pragma unroll
    for (int off = 32; off >= 1; off >>= 1) mx = fmaxf(mx, __shfl_xor(mx, off));
    const float thr = mx * 0.3f;

    int mymask = 0;
    float av[4] = {a4.x, a4.y, a4.z, a4.w};
    if (l < Q4) {
        #pragma unroll
        for (int j = 0; j < 4; ++j) {
            const int p = 4 * l + j;
            const bool m = av[j] > thr;
            mymask |= (m ? 1 : 0) << j;
            lab[p] = m ? p : SENT;
        }
    }
    asm volatile("s_waitcnt lgkmcnt(0)" ::: "memory");

    // Gauss-Seidel min-label propagation (8-connectivity). Monotone min
    // updates -> order-independent fixed point == reference's Jacobi result.
    for (;;) {
        int changed = 0;
        if (mymask) {
            #pragma unroll
            for (int j = 0; j < 4; ++j) {
                if (mymask & (1 << j)) {
                    const int p = 4 * l + j;
                    const int row = p / WW, col = p % WW;
                    const int cur = lab[p];
                    int m2 = cur;
                    #pragma unroll
                    for (int dr = -1; dr <= 1; ++dr) {
                        const int rr = row + dr;
                        if (rr < 0 || rr >= HH) continue;
                        #pragma unroll
                        for (int dc = -1; dc <= 1; ++dc) {
                            const int cc = col + dc;
                            if (cc < 0 || cc >= WW) continue;
                            m2 = min(m2, lab[rr * WW + cc]);
                        }
                    }
                    if (m2 < cur) { lab[p] = m2; changed = 1; }
                }
            }
        }
        asm volatile("s_waitcnt lgkmcnt(0)" ::: "memory");
        if (!__any(changed)) break;
    }

    // per-label counts
    cnt[l] = 0; cnt[l + 64] = 0; cnt[l + 128] = 0; cnt[l + 192] = 0;
    asm volatile("s_waitcnt lgkmcnt(0)" ::: "memory");
    if (l < Q4) {
        #pragma unroll
        for (int j = 0; j < 4; ++j)
            if (mymask & (1 << j)) atomicAdd(&cnt[lab[4 * l + j]], 1);
    }
    asm volatile("s_waitcnt lgkmcnt(0)" ::: "memory");

    // argmax(count), ties -> smallest label: key = cnt*256 + (255 - label)
    int key = 0;
    if (l < Q4) {
        #pragma unroll
        for (int j = 0; j < 4; ++j) {
            const int p = 4 * l + j;
            key = max(key, cnt[p] * 256 + (255 - p));
        }
    }
    #pragma unroll
    for (int off = 32; off >= 1; off >>= 1) key = max(key, __shfl_xor(key, off));
    const int best = 255 - (key & 255);
    const int bcnt = key >> 8;

    // bbox of selected component (unmasked pixels have lab==SENT != best)
    int mnr = HH, mxr = -1, mnc = WW, mxc = -1;
    if (l < Q4 && bcnt > 0) {
        #pragma unroll
        for (int j = 0; j < 4; ++j) {
            const int p = 4 * l + j;
            if (lab[p] == best) {
                const int row = p / WW, col = p % WW;
                mnr = min(mnr, row); mxr = max(mxr, row);
                mnc = min(mnc, col); mxc = max(mxc, col);
            }
        }
    }
    #pragma unroll
    for (int off = 32; off >= 1; off >>= 1) {
        mnr = min(mnr, __shfl_xor(mnr, off));
        mxr = max(mxr, __shfl_xor(mxr, off));
        mnc = min(mnc, __shfl_xor(mnc, off));
        mxc = max(mxc, __shfl_xor(mxc, off));
    }

    if (l == 0) {
        if (bcnt == 0) { mnr = 0; mxr = HH - 1; mnc = 0; mxc = WW - 1; }  // empty fallback
        out[b * 4 + 0] = max(mnr * 32 - 1, 0);
        out[b * 4 + 1] = max(mnc * 32 - 1, 0);
        out[b * 4 + 2] = (mxr + 1) * 32 - 1;
        out[b * 4 + 3] = (mxc + 1) * 32 - 1;
    }
}

extern "C" void kernel_launch(void* const* d_in, const int* in_sizes, int n_in,
                              void* d_out, int out_size, void* d_ws, size_t ws_size,
                              hipStream_t stream) {
    const float* fms = (const float*)d_in[0];
    int* out = (int*)d_out;
    float* partials = (float*)d_ws;   // 64*NCHUNK*196 floats = 1,605,632 B

    chansum_kernel<<<dim3(64 * NCHUNK), dim3(256), 0, stream>>>(fms, partials);
    bbox_kernel<<<dim3(64), dim3(64), 0, stream>>>(partials, out);
}

// Round 4
// 37.733 us; speedup vs baseline: 3.4137x; 1.0278x over previous
//
#include <hip/hip_runtime.h>

#define HH 14
#define WW 14
#define P 196          // HH*WW
#define SENT 196
#define CTOT 2048
#define NCHUNK 16
#define CCHUNK 128     // CTOT/NCHUNK
#define Q4 49          // P/4 float4 per channel row

// ---------------- kernel 1: partial channel sums (round-1 exact) ----------------
// grid = 64*NCHUNK = 1024 blocks, 256 threads. Block (b,k) sums channels
// [k*CCHUNK,(k+1)*CCHUNK) into partials[b*NCHUNK+k][196].
__global__ __launch_bounds__(256) void chansum_kernel(const float* __restrict__ fms,
                                                      float* __restrict__ partials) {
    const int blk = blockIdx.x;
    const int b = blk >> 4;       // /NCHUNK
    const int k = blk & 15;       // %NCHUNK
    const float4* __restrict__ base =
        (const float4*)(fms + ((size_t)b * CTOT + (size_t)k * CCHUNK) * P);

    __shared__ float lds[5 * P];
    const int t = threadIdx.x;

    if (t < 5 * Q4) {             // 245 active lanes
        const int q = t % Q4;     // float4 column within a channel row
        const int r = t / Q4;     // row-group 0..4
        float4 acc = {0.f, 0.f, 0.f, 0.f};
        #pragma unroll 4
        for (int c = r; c < CCHUNK; c += 5) {
            float4 v = base[c * Q4 + q];
            acc.x += v.x; acc.y += v.y; acc.z += v.z; acc.w += v.w;
        }
        const int o = r * P + q * 4;
        lds[o + 0] = acc.x; lds[o + 1] = acc.y;
        lds[o + 2] = acc.z; lds[o + 3] = acc.w;
    }
    __syncthreads();
    if (t < P) {
        float s = lds[t] + lds[P + t] + lds[2 * P + t] + lds[3 * P + t] + lds[4 * P + t];
        partials[(size_t)blk * P + t] = s;
    }
}

// ---------------- kernel 2: hybrid finisher ----------------
// grid = 64 blocks x 256 threads. Phase A: 196 threads sum the 16 partial
// chunks (coalesced, fully unrolled -> one latency exposure). ONE barrier.
// Then wave 0 alone runs the wave-synchronous finisher (proven in r2/r3):
// zero further __syncthreads, LDS ordering via s_waitcnt lgkmcnt(0).
__global__ __launch_bounds__(256) void bbox_kernel(const float* __restrict__ partials,
                                                   int* __restrict__ out) {
    const int b = blockIdx.x;
    const int t = threadIdx.x;

    __shared__ float att[P];
    __shared__ int lab[P];
    __shared__ int cnt[256];

    // ---- phase A: attention = sum over 16 chunks (4 waves active) ----
    if (t < P) {
        const float* pb = partials + (size_t)b * NCHUNK * P + t;
        float a = 0.f;
        #pragma unroll
        for (int k = 0; k < NCHUNK; ++k) a += pb[k * P];
        att[t] = a;
    }
    __syncthreads();
    if (t >= 64) return;          // waves 1..3 done; wave 0 finishes alone

    // ---- phase B: single-wave finisher ----
    const int l = t;              // lane 0..63; lanes 0..48 own pixel quads

    float4 a4 = {0.f, 0.f, 0.f, 0.f};
    if (l < Q4) a4 = *(const float4*)(att + 4 * l);
    float mx = (l < Q4) ? fmaxf(fmaxf(a4.x, a4.y), fmaxf(a4.z, a4.w)) : -1e30f;
    #pragma unroll
    for (int off = 32; off >= 1; off >>= 1) mx = fmaxf(mx, __shfl_xor(mx, off));
    const float thr = mx * 0.3f;

    int mymask = 0;
    float av[4] = {a4.x, a4.y, a4.z, a4.w};
    if (l < Q4) {
        #pragma unroll
        for (int j = 0; j < 4; ++j) {
            const int p = 4 * l + j;
            const bool m = av[j] > thr;
            mymask |= (m ? 1 : 0) << j;
            lab[p] = m ? p : SENT;
        }
    }
    asm volatile("s_waitcnt lgkmcnt(0)" ::: "memory");

    // Gauss-Seidel min-label propagation (8-connectivity). Monotone min
    // updates -> order-independent fixed point == reference's Jacobi result.
    for (;;) {
        int changed = 0;
        if (mymask) {
            #pragma unroll
            for (int j = 0; j < 4; ++j) {
                if (mymask & (1 << j)) {
                    const int p = 4 * l + j;
                    const int row = p / WW, col = p % WW;
                    const int cur = lab[p];
                    int m2 = cur;
                    #pragma unroll
                    for (int dr = -1; dr <= 1; ++dr) {
                        const int rr = row + dr;
                        if (rr < 0 || rr >= HH) continue;
                        #pragma unroll
                        for (int dc = -1; dc <= 1; ++dc) {
                            const int cc = col + dc;
                            if (cc < 0 || cc >= WW) continue;
                            m2 = min(m2, lab[rr * WW + cc]);
                        }
                    }
                    if (m2 < cur) { lab[p] = m2; changed = 1; }
                }
            }
        }
        asm volatile("s_waitcnt lgkmcnt(0)" ::: "memory");
        if (!__any(changed)) break;
    }

    // per-label counts
    cnt[l] = 0; cnt[l + 64] = 0; cnt[l + 128] = 0; cnt[l + 192] = 0;
    asm volatile("s_waitcnt lgkmcnt(0)" ::: "memory");
    if (l < Q4) {
        #pragma unroll
        for (int j = 0; j < 4; ++j)
            if (mymask & (1 << j)) atomicAdd(&cnt[lab[4 * l + j]], 1);
    }
    asm volatile("s_waitcnt lgkmcnt(0)" ::: "memory");

    // argmax(count), ties -> smallest label: key = cnt*256 + (255 - label)
    int key = 0;
    if (l < Q4) {
        #pragma unroll
        for (int j = 0; j < 4; ++j) {
            const int p = 4 * l + j;
            key = max(key, cnt[p] * 256 + (255 - p));
        }
    }
    #pragma unroll
    for (int off = 32; off >= 1; off >>= 1) key = max(key, __shfl_xor(key, off));
    const int best = 255 - (key & 255);
    const int bcnt = key >> 8;

    // bbox of selected component (unmasked pixels have lab==SENT != best)
    int mnr = HH, mxr = -1, mnc = WW, mxc = -1;
    if (l < Q4 && bcnt > 0) {
        #pragma unroll
        for (int j = 0; j < 4; ++j) {
            const int p = 4 * l + j;
            if (lab[p] == best) {
                const int row = p / WW, col = p % WW;
                mnr = min(mnr, row); mxr = max(mxr, row);
                mnc = min(mnc, col); mxc = max(mxc, col);
            }
        }
    }
    #pragma unroll
    for (int off = 32; off >= 1; off >>= 1) {
        mnr = min(mnr, __shfl_xor(mnr, off));
        mxr = max(mxr, __shfl_xor(mxr, off));
        mnc = min(mnc, __shfl_xor(mnc, off));
        mxc = max(mxc, __shfl_xor(mxc, off));
    }

    if (l == 0) {
        if (bcnt == 0) { mnr = 0; mxr = HH - 1; mnc = 0; mxc = WW - 1; }  // empty fallback
        out[b * 4 + 0] = max(mnr * 32 - 1, 0);
        out[b * 4 + 1] = max(mnc * 32 - 1, 0);
        out[b * 4 + 2] = (mxr + 1) * 32 - 1;
        out[b * 4 + 3] = (mxc + 1) * 32 - 1;
    }
}

extern "C" void kernel_launch(void* const* d_in, const int* in_sizes, int n_in,
                              void* d_out, int out_size, void* d_ws, size_t ws_size,
                              hipStream_t stream) {
    const float* fms = (const float*)d_in[0];
    int* out = (int*)d_out;
    float* partials = (float*)d_ws;   // 64*NCHUNK*196 floats = 802,816 B

    chansum_kernel<<<dim3(64 * NCHUNK), dim3(256), 0, stream>>>(fms, partials);
    bbox_kernel<<<dim3(64), dim3(256), 0, stream>>>(partials, out);
}